// Round 1
// baseline (106.805 us; speedup 1.0000x reference)
//
#include <hip/hip_runtime.h>

#define Bn 2
#define Cn 3
#define Hn 160
#define Wn 160
#define SPANc 11
#define Kc 23
#define HWn (Hn * Wn)
#define LAMc 0.15f
#define TILE 16
#define PARTS 4
#define DI_CHUNK 6   // ceil(23/4)

__device__ __forceinline__ float wave_reduce64(float v) {
#pragma unroll
    for (int off = 32; off > 0; off >>= 1) v += __shfl_down(v, off, 64);
    return v;
}

__global__ void zero_acc_kernel(double* acc) { *acc = 0.0; }

// One thread per pixel: softmax -> y_hat, pack interleaved record, CE partial sum.
__global__ __launch_bounds__(256) void prep_kernel(
    const float* __restrict__ logit, const int* __restrict__ target,
    const float* __restrict__ image, const float* __restrict__ srcmap,
    const float* __restrict__ dstmap, float* __restrict__ pix,
    double* __restrict__ acc)
{
    int p = blockIdx.x * 256 + threadIdx.x;   // 0 .. B*HW-1
    int b = p / HWn;
    int r = p - b * HWn;

    const float* lg = logit + (size_t)b * Cn * HWn + r;
    float l0 = lg[0], l1 = lg[HWn], l2 = lg[2 * HWn];
    float m = fmaxf(l0, fmaxf(l1, l2));
    float e0 = __expf(l0 - m), e1 = __expf(l1 - m), e2 = __expf(l2 - m);
    float s = e0 + e1 + e2;
    float inv = 1.0f / s;
    float y0 = e0 * inv, y1 = e1 * inv, y2 = e2 * inv;
    float lse = m + __logf(s);

    const float* im = image + (size_t)b * 3 * HWn + r;
    float i0 = im[0], i1 = im[HWn], i2 = im[2 * HWn];
    float sv = srcmap[p];

    float4* op = (float4*)(pix + (size_t)p * 8);
    op[0] = make_float4(i0, i1, i2, sv);
    op[1] = make_float4(y0, y1, y2, 0.0f);

    int t = target[p];
    float lt = (t == 0) ? l0 : ((t == 1) ? l1 : l2);
    float ce = (lse - lt) * dstmap[p];

    float v = wave_reduce64(ce);
    __shared__ float wsum[4];
    int tid = threadIdx.x;
    if ((tid & 63) == 0) wsum[tid >> 6] = v;
    __syncthreads();
    if (tid == 0) atomicAdd(acc, (double)(wsum[0] + wsum[1] + wsum[2] + wsum[3]));
}

// Window loop. Grid: (W/16, (H/16)*B, PARTS). Each part handles a di-chunk.
__global__ __launch_bounds__(256) void gcrf_kernel(
    const float* __restrict__ pix, const float* __restrict__ dstmap,
    double* __restrict__ acc)
{
    int j = blockIdx.x * TILE + threadIdx.x;
    int by = blockIdx.y;
    int b = by / (Hn / TILE);
    int i = (by - b * (Hn / TILE)) * TILE + threadIdx.y;
    int part = blockIdx.z;
    int di0 = part * DI_CHUNK;
    int di1 = di0 + DI_CHUNK; if (di1 > Kc) di1 = Kc;

    const float* base = pix + (size_t)b * HWn * 8;
    const float4* cp = (const float4*)(base + ((size_t)(i * Wn + j)) * 8);
    float4 ca = cp[0];   // img0,img1,img2,src(center, unused)
    float4 cb = cp[1];   // y0,y1,y2,pad
    float mdst = 1.0f - dstmap[(size_t)b * HWn + i * Wn + j];

    // Separable k_xy: fy[dj] depends only on (j, dj). Register array, static idx.
    float fy[Kc];
#pragma unroll
    for (int dj = 0; dj < Kc; ++dj) {
        int pj = j + dj - SPANc;
        float d = (float)j - (float)pj * (1.0f / 6.0f);
        fy[dj] = __expf(-0.5f * d * d);
    }

    float eg0 = 0.0f, eg1 = 0.0f, eg2 = 0.0f;
    if (mdst != 0.0f) {
        for (int di = di0; di < di1; ++di) {
            int pi = i + di - SPANc;
            if (pi < 0 || pi >= Hn) continue;
            float dx = (float)i - (float)pi * (1.0f / 6.0f);
            float fx = __expf(-0.5f * dx * dx);
            const float4* rowp = (const float4*)(base + (size_t)pi * Wn * 8);
#pragma unroll
            for (int dj = 0; dj < Kc; ++dj) {
                int pj = j + dj - SPANc;
                if (pj < 0 || pj >= Wn) continue;
                float4 pa = rowp[pj * 2];      // img0,img1,img2,src
                float4 pb = rowp[pj * 2 + 1];  // y0,y1,y2,pad
                float d0 = fmaf(pa.x, -10.0f, ca.x);
                float d1 = fmaf(pa.y, -10.0f, ca.y);
                float d2 = fmaf(pa.z, -10.0f, ca.z);
                float ss = fmaf(d0, d0, fmaf(d1, d1, d2 * d2));
                float krgb = __expf(-0.5f * ss);
                float kg = (krgb + fx * fy[dj]) * pa.w;
                eg0 = fmaf(kg, pb.x, eg0);
                eg1 = fmaf(kg, pb.y, eg1);
                eg2 = fmaf(kg, pb.z, eg2);
            }
        }
    }

    float contrib = LAMc * mdst *
        (eg0 * (1.0f - cb.x) + eg1 * (1.0f - cb.y) + eg2 * (1.0f - cb.z));

    float v = wave_reduce64(contrib);
    __shared__ float wsum[4];
    int tid = threadIdx.y * TILE + threadIdx.x;
    if ((tid & 63) == 0) wsum[tid >> 6] = v;
    __syncthreads();
    if (tid == 0) atomicAdd(acc, (double)(wsum[0] + wsum[1] + wsum[2] + wsum[3]));
}

__global__ void finalize_kernel(const double* __restrict__ acc, float* __restrict__ out) {
    out[0] = (float)(acc[0] * (1.0 / (double)(Bn * HWn)));
}

extern "C" void kernel_launch(void* const* d_in, const int* in_sizes, int n_in,
                              void* d_out, int out_size, void* d_ws, size_t ws_size,
                              hipStream_t stream)
{
    const float* logit  = (const float*)d_in[0];
    const int*   target = (const int*)d_in[1];
    const float* image  = (const float*)d_in[2];
    const float* srcmap = (const float*)d_in[3];
    const float* dstmap = (const float*)d_in[4];
    float* out = (float*)d_out;

    double* acc = (double*)d_ws;
    float*  pix = (float*)((char*)d_ws + 16);   // 16B-aligned, B*HW*8 floats = 1.6 MB

    zero_acc_kernel<<<1, 1, 0, stream>>>(acc);
    prep_kernel<<<(Bn * HWn) / 256, 256, 0, stream>>>(logit, target, image, srcmap,
                                                      dstmap, pix, acc);
    dim3 grid(Wn / TILE, (Hn / TILE) * Bn, PARTS);
    dim3 blk(TILE, TILE);
    gcrf_kernel<<<grid, blk, 0, stream>>>(pix, dstmap, acc);
    finalize_kernel<<<1, 1, 0, stream>>>(acc, out);
}

// Round 2
// 105.847 us; speedup vs baseline: 1.0090x; 1.0090x over previous
//
#include <hip/hip_runtime.h>

#define Bn 2
#define Cn 3
#define Hn 160
#define Wn 160
#define SPANc 11
#define Kc 23
#define HWn (Hn * Wn)
#define PW 182                 // padded dim: 160 + 2*11
#define LAMc 0.15f
#define TJ 32                  // j-tile width
#define Gc 4                   // centers per thread (vertical)
#define TI 32                  // i-tile height = 8 ty-groups * Gc

__device__ __forceinline__ float wave_reduce64(float v) {
#pragma unroll
    for (int off = 32; off > 0; off >>= 1) v += __shfl_down(v, off, 64);
    return v;
}

// Zero the padded pixel buffer (halo must be 0: src=0,y=0 => zero contribution)
// and the accumulator.
__global__ __launch_bounds__(256) void zero_pix_kernel(float4* __restrict__ pix,
                                                       double* __restrict__ acc) {
    int idx = blockIdx.x * 256 + threadIdx.x;
    const int total = Bn * PW * PW * 2;   // 132,496 float4
    if (idx < total) pix[idx] = make_float4(0.f, 0.f, 0.f, 0.f);
    if (idx == 0) *acc = 0.0;
}

// Per pixel: softmax -> y_hat, pack record into padded layout, CE partial sum.
// Record (2 x float4): [img0,img1,img2,src | y0,y1,y2, 1-dst]
__global__ __launch_bounds__(256) void prep_kernel(
    const float* __restrict__ logit, const int* __restrict__ target,
    const float* __restrict__ image, const float* __restrict__ srcmap,
    const float* __restrict__ dstmap, float* __restrict__ pix,
    double* __restrict__ acc)
{
    int p = blockIdx.x * 256 + threadIdx.x;   // 0 .. B*HW-1
    int b = p / HWn;
    int r = p - b * HWn;
    int i = r / Wn;
    int j = r - i * Wn;

    const float* lg = logit + (size_t)b * Cn * HWn + r;
    float l0 = lg[0], l1 = lg[HWn], l2 = lg[2 * HWn];
    float m = fmaxf(l0, fmaxf(l1, l2));
    float e0 = __expf(l0 - m), e1 = __expf(l1 - m), e2 = __expf(l2 - m);
    float s = e0 + e1 + e2;
    float inv = 1.0f / s;
    float lse = m + __logf(s);

    const float* im = image + (size_t)b * 3 * HWn + r;
    float i0v = im[0], i1v = im[HWn], i2v = im[2 * HWn];
    float sv = srcmap[p];
    float dv = dstmap[p];

    size_t rec = ((size_t)b * PW + (i + SPANc)) * PW + (j + SPANc);
    float4* op = (float4*)pix + rec * 2;
    op[0] = make_float4(i0v, i1v, i2v, sv);
    op[1] = make_float4(e0 * inv, e1 * inv, e2 * inv, 1.0f - dv);

    int t = target[p];
    float lt = (t == 0) ? l0 : ((t == 1) ? l1 : l2);
    float ce = (lse - lt) * dv;

    float v = wave_reduce64(ce);
    __shared__ float wsum[4];
    int tid = threadIdx.x;
    if ((tid & 63) == 0) wsum[tid >> 6] = v;
    __syncthreads();
    if (tid == 0) atomicAdd(acc, (double)(wsum[0] + wsum[1] + wsum[2] + wsum[3]));
}

// Window kernel. Grid: (W/TJ=5, (H/TI=5)*B=10, Kc=23). Block (32,8).
// Each thread: 4 vertically-adjacent centers, one dj column, all 23 di rows.
// One record load serves up to 4 centers (3.54x L1 traffic reduction).
__global__ __launch_bounds__(256) void gcrf_kernel(
    const float* __restrict__ pixf, double* __restrict__ acc)
{
    int tx = threadIdx.x;                 // 0..31 (j)
    int ty = threadIdx.y;                 // 0..7  (i-group)
    int j  = blockIdx.x * TJ + tx;
    int by = blockIdx.y;
    int b  = by / 5;
    int it = by - b * 5;
    int i0 = it * TI + ty * Gc;           // first center row of this thread
    int dj = blockIdx.z;                  // 0..22

    const float4* base = (const float4*)pixf + (size_t)b * PW * PW * 2;
    const float4* crec = base + (((size_t)(i0 + SPANc)) * PW + (j + SPANc)) * 2;

    // center image colors (record slot 0) for 4 centers
    float4 cA[Gc];
#pragma unroll
    for (int c = 0; c < Gc; ++c) cA[c] = crec[(size_t)c * PW * 2];

    // k_xy is negligible (< 2.3e-29) unless both i<16 and j<16 (source-bug form:
    // d = center - patch/6 grows ~5*idx/6). i0 is a multiple of 4 so i0<16 <=> all 4 centers <16.
    bool xy_on = (j < 16) && (i0 < 16);
    float dy = (float)j - (float)(j + dj - SPANc) * (1.0f / 6.0f);
    float dy2 = dy * dy;

    float eg[Gc][3];
#pragma unroll
    for (int c = 0; c < Gc; ++c) { eg[c][0] = 0.f; eg[c][1] = 0.f; eg[c][2] = 0.f; }

    // column of records at padded (row = i0 + r, col = j + dj), r = 0..25
    const float4* colp = base + ((size_t)i0 * PW + (j + dj)) * 2;

#pragma unroll
    for (int r = 0; r < Kc + Gc - 1; ++r) {
        float4 pa = colp[0];
        float4 pb = colp[1];
        colp += PW * 2;
        int pi = i0 - SPANc + r;
#pragma unroll
        for (int c = 0; c < Gc; ++c) {
            if (r < c || r > c + Kc - 1) continue;   // static, dead-code eliminated
            float d0 = fmaf(pa.x, -10.0f, cA[c].x);
            float d1 = fmaf(pa.y, -10.0f, cA[c].y);
            float d2 = fmaf(pa.z, -10.0f, cA[c].z);
            float ss = fmaf(d0, d0, fmaf(d1, d1, d2 * d2));
            float k = __expf(-0.5f * ss);
            if (xy_on) {
                float dx = (float)(i0 + c) - (float)pi * (1.0f / 6.0f);
                k += __expf(-0.5f * fmaf(dx, dx, dy2));
            }
            float kg = k * pa.w;
            eg[c][0] = fmaf(kg, pb.x, eg[c][0]);
            eg[c][1] = fmaf(kg, pb.y, eg[c][1]);
            eg[c][2] = fmaf(kg, pb.z, eg[c][2]);
        }
    }

    // epilogue: center y + (1-dst) live in record slot 1
    float contrib = 0.0f;
#pragma unroll
    for (int c = 0; c < Gc; ++c) {
        float4 cb = crec[(size_t)c * PW * 2 + 1];
        contrib += cb.w * (eg[c][0] * (1.0f - cb.x) +
                           eg[c][1] * (1.0f - cb.y) +
                           eg[c][2] * (1.0f - cb.z));
    }
    contrib *= LAMc;

    float v = wave_reduce64(contrib);
    __shared__ float wsum[4];
    int tid = ty * TJ + tx;
    if ((tid & 63) == 0) wsum[tid >> 6] = v;
    __syncthreads();
    if (tid == 0) atomicAdd(acc, (double)(wsum[0] + wsum[1] + wsum[2] + wsum[3]));
}

__global__ void finalize_kernel(const double* __restrict__ acc, float* __restrict__ out) {
    out[0] = (float)(acc[0] * (1.0 / (double)(Bn * HWn)));
}

extern "C" void kernel_launch(void* const* d_in, const int* in_sizes, int n_in,
                              void* d_out, int out_size, void* d_ws, size_t ws_size,
                              hipStream_t stream)
{
    const float* logit  = (const float*)d_in[0];
    const int*   target = (const int*)d_in[1];
    const float* image  = (const float*)d_in[2];
    const float* srcmap = (const float*)d_in[3];
    const float* dstmap = (const float*)d_in[4];
    float* out = (float*)d_out;

    double* acc = (double*)d_ws;
    float*  pix = (float*)((char*)d_ws + 256);   // padded records, 2.12 MB

    const int total4 = Bn * PW * PW * 2;
    zero_pix_kernel<<<(total4 + 255) / 256, 256, 0, stream>>>((float4*)pix, acc);
    prep_kernel<<<(Bn * HWn) / 256, 256, 0, stream>>>(logit, target, image, srcmap,
                                                      dstmap, pix, acc);
    dim3 grid(Wn / TJ, (Hn / TI) * Bn, Kc);
    dim3 blk(TJ, 8);
    gcrf_kernel<<<grid, blk, 0, stream>>>(pix, acc);
    finalize_kernel<<<1, 1, 0, stream>>>(acc, out);
}

// Round 5
// 101.767 us; speedup vs baseline: 1.0495x; 1.0401x over previous
//
#include <hip/hip_runtime.h>

#define Bn 2
#define Cn 3
#define Hn 160
#define Wn 160
#define SPANc 11
#define Kc 23
#define HWn (Hn * Wn)
#define PW 182                 // padded dim: 160 + 2*11
#define LAMc 0.15f
#define TJ 32                  // j-tile width (= lanes 0..31)
#define Gc 4                   // centers per thread (vertical)
#define TI 32                  // i-tile height = 8 ty-groups * Gc
#define NROW (TI + Kc - 1)     // 54 staged rows
#define NREC (NROW * TJ)       // 1728 records in LDS
#define CEXP (-0.72134752f)    // -0.5 * log2(e)

__device__ __forceinline__ float wave_reduce64(float v) {
#pragma unroll
    for (int off = 32; off > 0; off >>= 1) v += __shfl_down(v, off, 64);
    return v;
}

// Zero padded record buffers (halo must be 0 => ys=0 => zero contribution) + acc.
__global__ __launch_bounds__(256) void zero_pix_kernel(float4* __restrict__ gA,
                                                       float2* __restrict__ gB,
                                                       double* __restrict__ acc) {
    int idx = blockIdx.x * 256 + threadIdx.x;
    const int total = Bn * PW * PW;        // 66,248 records
    if (idx < total) {
        gA[idx] = make_float4(0.f, 0.f, 0.f, 0.f);
        gB[idx] = make_float2(0.f, 0.f);
    }
    if (idx == 0) *acc = 0.0;
}

// Per pixel: softmax, pack records gA=[img0,img1,img2,ys0], gB=[ys1,ys2]
// (ys = src*y), cvec = lam*(1-dst)*(1-y), CE partial sum.
__global__ __launch_bounds__(256) void prep_kernel(
    const float* __restrict__ logit, const int* __restrict__ target,
    const float* __restrict__ image, const float* __restrict__ srcmap,
    const float* __restrict__ dstmap, float4* __restrict__ gA,
    float2* __restrict__ gB, float4* __restrict__ cvec, double* __restrict__ acc)
{
    int p = blockIdx.x * 256 + threadIdx.x;   // 0 .. B*HW-1
    int b = p / HWn;
    int r = p - b * HWn;
    int i = r / Wn;
    int j = r - i * Wn;

    const float* lg = logit + (size_t)b * Cn * HWn + r;
    float l0 = lg[0], l1 = lg[HWn], l2 = lg[2 * HWn];
    float m = fmaxf(l0, fmaxf(l1, l2));
    float e0 = __expf(l0 - m), e1 = __expf(l1 - m), e2 = __expf(l2 - m);
    float s = e0 + e1 + e2;
    float inv = 1.0f / s;
    float y0 = e0 * inv, y1 = e1 * inv, y2 = e2 * inv;
    float lse = m + __logf(s);

    const float* im = image + (size_t)b * 3 * HWn + r;
    float i0v = im[0], i1v = im[HWn], i2v = im[2 * HWn];
    float sv = srcmap[p];
    float dv = dstmap[p];

    size_t rec = ((size_t)b * PW + (i + SPANc)) * PW + (j + SPANc);
    gA[rec] = make_float4(i0v, i1v, i2v, sv * y0);
    gB[rec] = make_float2(sv * y1, sv * y2);

    float md = LAMc * (1.0f - dv);
    cvec[p] = make_float4(md * (1.0f - y0), md * (1.0f - y1), md * (1.0f - y2), 0.0f);

    int t = target[p];
    float lt = (t == 0) ? l0 : ((t == 1) ? l1 : l2);
    float ce = (lse - lt) * dv;

    float v = wave_reduce64(ce);
    __shared__ float wsum[4];
    int tid = threadIdx.x;
    if ((tid & 63) == 0) wsum[tid >> 6] = v;
    __syncthreads();
    if (tid == 0) atomicAdd(acc, (double)(wsum[0] + wsum[1] + wsum[2] + wsum[3]));
}

// Window kernel. Grid: (5, 5*B, 23). Block (32,8). One dj column per block.
// Stage 54x32 records (41.5 KB LDS) with coalesced loads, then each thread
// computes 4 vertically-adjacent centers over 23 di taps from LDS only.
__global__ __launch_bounds__(256) void gcrf_kernel(
    const float4* __restrict__ gA, const float2* __restrict__ gB,
    const float4* __restrict__ cvec, double* __restrict__ acc)
{
    __shared__ float4 sA[NREC];   // img0,img1,img2,ys0
    __shared__ float2 sB[NREC];   // ys1,ys2

    int tx = threadIdx.x;                 // 0..31 (j)
    int ty = threadIdx.y;                 // 0..7  (i-group)
    int tid = ty * TJ + tx;
    int jx = blockIdx.x;
    int j  = jx * TJ + tx;
    int by = blockIdx.y;
    int b  = by / 5;
    int it = by - b * 5;
    int i0g = it * TI + ty * Gc;          // first center row of this thread
    int dj = blockIdx.z;                  // 0..22

    size_t base = (size_t)b * PW * PW;
    int R0 = it * TI;                     // padded row base of stage region
    int C0 = jx * TJ + dj;                // padded col base
    size_t g0 = base + (size_t)R0 * PW + C0;

    for (int n = tid; n < NREC; n += 256) {
        int rr = n >> 5, cc = n & 31;
        size_t gi = g0 + (size_t)rr * PW + cc;
        sA[n] = gA[gi];
        sB[n] = gB[gi];
    }
    __syncthreads();

    // center colors from LDS (center at local row ty*Gc + c + SPANc, col tx)
    int lrow0 = ty * Gc;
    float cA0[Gc], cA1[Gc], cA2[Gc];
#pragma unroll
    for (int c = 0; c < Gc; ++c) {
        float4 cr = sA[(lrow0 + c + SPANc) * TJ + tx];
        cA0[c] = cr.x; cA1[c] = cr.y; cA2[c] = cr.z;
    }

    // k_xy < 2.3e-29 unless both i<16 and j<16 (source-bug form: d = c - p/6)
    bool xy_on = (j < 16) && (i0g < 16);
    float dy = (float)j - (float)(j + dj - SPANc) * (1.0f / 6.0f);
    float dy2 = dy * dy;

    float eg[Gc][3];
#pragma unroll
    for (int c = 0; c < Gc; ++c) { eg[c][0] = 0.f; eg[c][1] = 0.f; eg[c][2] = 0.f; }

#pragma unroll
    for (int r = 0; r < Kc + Gc - 1; ++r) {
        float4 pa = sA[(lrow0 + r) * TJ + tx];
        float2 pb = sB[(lrow0 + r) * TJ + tx];
        int pi = i0g + r - SPANc;
#pragma unroll
        for (int c = 0; c < Gc; ++c) {
            if (r < c || r > c + Kc - 1) continue;   // static, dead-code eliminated
            float d0 = fmaf(pa.x, -10.0f, cA0[c]);
            float d1 = fmaf(pa.y, -10.0f, cA1[c]);
            float d2 = fmaf(pa.z, -10.0f, cA2[c]);
            float ss = fmaf(d0, d0, fmaf(d1, d1, d2 * d2));
            float k = exp2f(ss * CEXP);
            if (xy_on) {
                float dx = (float)(i0g + c) - (float)pi * (1.0f / 6.0f);
                k += exp2f(fmaf(dx, dx, dy2) * CEXP);
            }
            eg[c][0] = fmaf(k, pa.w, eg[c][0]);
            eg[c][1] = fmaf(k, pb.x, eg[c][1]);
            eg[c][2] = fmaf(k, pb.y, eg[c][2]);
        }
    }

    // epilogue: cvec already holds lam*(1-dst)*(1-y_c)
    const float4* cv = cvec + ((size_t)b * HWn + (size_t)i0g * Wn + j);
    float contrib = 0.0f;
#pragma unroll
    for (int c = 0; c < Gc; ++c) {
        float4 t = cv[(size_t)c * Wn];
        contrib += eg[c][0] * t.x + eg[c][1] * t.y + eg[c][2] * t.z;
    }

    float v = wave_reduce64(contrib);
    __shared__ float wsum[4];
    if ((tid & 63) == 0) wsum[tid >> 6] = v;
    __syncthreads();
    if (tid == 0) atomicAdd(acc, (double)(wsum[0] + wsum[1] + wsum[2] + wsum[3]));
}

__global__ void finalize_kernel(const double* __restrict__ acc, float* __restrict__ out) {
    out[0] = (float)(acc[0] * (1.0 / (double)(Bn * HWn)));
}

extern "C" void kernel_launch(void* const* d_in, const int* in_sizes, int n_in,
                              void* d_out, int out_size, void* d_ws, size_t ws_size,
                              hipStream_t stream)
{
    const float* logit  = (const float*)d_in[0];
    const int*   target = (const int*)d_in[1];
    const float* image  = (const float*)d_in[2];
    const float* srcmap = (const float*)d_in[3];
    const float* dstmap = (const float*)d_in[4];
    float* out = (float*)d_out;

    const size_t NRECG = (size_t)Bn * PW * PW;   // 66,248 padded records
    double* acc  = (double*)d_ws;
    float4* gA   = (float4*)((char*)d_ws + 256);
    float2* gB   = (float2*)((char*)d_ws + 256 + NRECG * 16);
    float4* cvec = (float4*)((char*)d_ws + 256 + NRECG * 16 + NRECG * 8);

    zero_pix_kernel<<<((int)NRECG + 255) / 256, 256, 0, stream>>>(gA, gB, acc);
    prep_kernel<<<(Bn * HWn) / 256, 256, 0, stream>>>(logit, target, image, srcmap,
                                                      dstmap, gA, gB, cvec, acc);
    dim3 grid(Wn / TJ, (Hn / TI) * Bn, Kc);
    dim3 blk(TJ, 8);
    gcrf_kernel<<<grid, blk, 0, stream>>>(gA, gB, cvec, acc);
    finalize_kernel<<<1, 1, 0, stream>>>(acc, out);
}

// Round 6
// 92.126 us; speedup vs baseline: 1.1593x; 1.1046x over previous
//
#include <hip/hip_runtime.h>

#define Bn 2
#define Cn 3
#define Hn 160
#define Wn 160
#define SPANc 11
#define Kc 23
#define HWn (Hn * Wn)
#define PW 182                 // padded dim: 160 + 2*11
#define PP (PW * PW)
#define LAMc 0.15f
#define TJ 32                  // j-tile width (= lanes 0..31)
#define Gc 4                   // centers per thread (vertical)
#define TI 32                  // i-tile height = 8 ty-groups * Gc
#define NROW (TI + Kc - 1)     // 54 staged rows
#define NREC (NROW * TJ)       // 1728 records in LDS
#define CEXP (-0.72134752f)    // -0.5 * log2(e)
#define NPREP ((Bn * PP + 255) / 256)   // 259 prep blocks

__device__ __forceinline__ float wave_reduce64(float v) {
#pragma unroll
    for (int off = 32; off > 0; off >>= 1) v += __shfl_down(v, off, 64);
    return v;
}

// Fused: zero halo + softmax/pack interior + CE block-partials + zero acc.
// Records: gA=[img0,img1,img2,ys0], gB=[ys1,ys2] (ys = src*y); halo = 0.
__global__ __launch_bounds__(256) void prep_kernel(
    const float* __restrict__ logit, const int* __restrict__ target,
    const float* __restrict__ image, const float* __restrict__ srcmap,
    const float* __restrict__ dstmap, float4* __restrict__ gA,
    float2* __restrict__ gB, float4* __restrict__ cvec,
    float* __restrict__ pc, double* __restrict__ acc)
{
    int idx = blockIdx.x * 256 + threadIdx.x;
    float ce = 0.0f;
    if (idx < Bn * PP) {
        int b   = idx / PP;
        int rem = idx - b * PP;
        int ip  = rem / PW;
        int jp  = rem - ip * PW;
        int i = ip - SPANc, j = jp - SPANc;
        if ((unsigned)i < (unsigned)Hn && (unsigned)j < (unsigned)Wn) {
            int r = i * Wn + j;
            int p = b * HWn + r;
            const float* lg = logit + (size_t)b * Cn * HWn + r;
            float l0 = lg[0], l1 = lg[HWn], l2 = lg[2 * HWn];
            float m = fmaxf(l0, fmaxf(l1, l2));
            float e0 = __expf(l0 - m), e1 = __expf(l1 - m), e2 = __expf(l2 - m);
            float s = e0 + e1 + e2;
            float inv = 1.0f / s;
            float y0 = e0 * inv, y1 = e1 * inv, y2 = e2 * inv;
            float lse = m + __logf(s);

            const float* im = image + (size_t)b * 3 * HWn + r;
            float i0v = im[0], i1v = im[HWn], i2v = im[2 * HWn];
            float sv = srcmap[p];
            float dv = dstmap[p];

            gA[idx] = make_float4(i0v, i1v, i2v, sv * y0);
            gB[idx] = make_float2(sv * y1, sv * y2);

            float md = LAMc * (1.0f - dv);
            cvec[p] = make_float4(md * (1.0f - y0), md * (1.0f - y1),
                                  md * (1.0f - y2), 0.0f);

            int t = target[p];
            float lt = (t == 0) ? l0 : ((t == 1) ? l1 : l2);
            ce = (lse - lt) * dv;
        } else {
            gA[idx] = make_float4(0.f, 0.f, 0.f, 0.f);
            gB[idx] = make_float2(0.f, 0.f);
        }
    }
    if (idx == 0) *acc = 0.0;   // gcrf launches after this kernel completes

    float v = wave_reduce64(ce);
    __shared__ float wsum[4];
    int tid = threadIdx.x;
    if ((tid & 63) == 0) wsum[tid >> 6] = v;
    __syncthreads();
    if (tid == 0) pc[blockIdx.x] = wsum[0] + wsum[1] + wsum[2] + wsum[3];
}

__device__ __forceinline__ void tap(const float4 pa, const float2 pb,
                                    float cA0, float cA1, float cA2,
                                    bool xy_on, float dy2, float dxv,
                                    float& e0, float& e1, float& e2)
{
    float d0 = fmaf(pa.x, -10.0f, cA0);
    float d1 = fmaf(pa.y, -10.0f, cA1);
    float d2 = fmaf(pa.z, -10.0f, cA2);
    float ss = fmaf(d0, d0, fmaf(d1, d1, d2 * d2));
    float k = exp2f(ss * CEXP);
    if (xy_on) k += exp2f(fmaf(dxv, dxv, dy2) * CEXP);   // exec-masked, skipped by 96% of blocks
    e0 = fmaf(k, pa.w, e0);
    e1 = fmaf(k, pb.x, e1);
    e2 = fmaf(k, pb.y, e2);
}

// Window kernel. Grid: (5, 5*B, 23). Block (32,8). One dj column per block.
// Stage 54x32 records (41.5 KB LDS), then 4 vertically-adjacent centers per
// thread over 23 di taps. r-loop: static prologue/epilogue, rolled main body
// (r=3..22: all 4 centers active) to keep VGPR pressure low.
__global__ __launch_bounds__(256) void gcrf_kernel(
    const float4* __restrict__ gA, const float2* __restrict__ gB,
    const float4* __restrict__ cvec, double* __restrict__ acc)
{
    __shared__ float4 sA[NREC];   // img0,img1,img2,ys0
    __shared__ float2 sB[NREC];   // ys1,ys2

    int tx = threadIdx.x;                 // 0..31 (j)
    int ty = threadIdx.y;                 // 0..7  (i-group)
    int tid = ty * TJ + tx;
    int jx = blockIdx.x;
    int j  = jx * TJ + tx;
    int by = blockIdx.y;
    int b  = by / 5;
    int it = by - b * 5;
    int i0g = it * TI + ty * Gc;          // first center row of this thread
    int dj = blockIdx.z;                  // 0..22

    size_t g0 = (size_t)b * PP + (size_t)(it * TI) * PW + (jx * TJ + dj);
    for (int n = tid; n < NREC; n += 256) {
        int rr = n >> 5, cc = n & 31;
        size_t gi = g0 + (size_t)rr * PW + cc;
        sA[n] = gA[gi];
        sB[n] = gB[gi];
    }
    __syncthreads();

    int lbase = ty * Gc * TJ + tx;        // LDS index of (local row ty*Gc, col tx)
    float cA0[Gc], cA1[Gc], cA2[Gc];
#pragma unroll
    for (int c = 0; c < Gc; ++c) {
        float4 cr = sA[lbase + (c + SPANc) * TJ];
        cA0[c] = cr.x; cA1[c] = cr.y; cA2[c] = cr.z;
    }

    // k_xy < 2.3e-29 unless both i<16 and j<16 (source-bug form: d = c - p/6)
    bool xy_on = (j < 16) && (i0g < 16);
    float dy = (float)j - (float)(j + dj - SPANc) * (1.0f / 6.0f);
    float dy2 = dy * dy;
    float fi0 = (float)i0g;

    float eg[Gc][3];
#pragma unroll
    for (int c = 0; c < Gc; ++c) { eg[c][0] = 0.f; eg[c][1] = 0.f; eg[c][2] = 0.f; }

    // prologue r=0..2: center c active iff c <= r
#pragma unroll
    for (int r = 0; r < 3; ++r) {
        float4 pa = sA[lbase + r * TJ];
        float2 pb = sB[lbase + r * TJ];
        float fpi = fi0 + (float)(r - SPANc);
#pragma unroll
        for (int c = 0; c < 3; ++c) {
            if (c > r) continue;
            tap(pa, pb, cA0[c], cA1[c], cA2[c], xy_on, dy2,
                fi0 + (float)c - fpi * (1.0f / 6.0f), eg[c][0], eg[c][1], eg[c][2]);
        }
    }
    // main r=3..22: all 4 centers active
#pragma unroll 2
    for (int r = 3; r <= 22; ++r) {
        float4 pa = sA[lbase + r * TJ];
        float2 pb = sB[lbase + r * TJ];
        float fpi = fi0 + (float)(r - SPANc);
#pragma unroll
        for (int c = 0; c < Gc; ++c) {
            tap(pa, pb, cA0[c], cA1[c], cA2[c], xy_on, dy2,
                fi0 + (float)c - fpi * (1.0f / 6.0f), eg[c][0], eg[c][1], eg[c][2]);
        }
    }
    // epilogue r=23..25: center c active iff c >= r-22
#pragma unroll
    for (int r = 23; r <= 25; ++r) {
        float4 pa = sA[lbase + r * TJ];
        float2 pb = sB[lbase + r * TJ];
        float fpi = fi0 + (float)(r - SPANc);
#pragma unroll
        for (int c = 1; c < Gc; ++c) {
            if (c < r - 22) continue;
            tap(pa, pb, cA0[c], cA1[c], cA2[c], xy_on, dy2,
                fi0 + (float)c - fpi * (1.0f / 6.0f), eg[c][0], eg[c][1], eg[c][2]);
        }
    }

    // epilogue: cvec already holds lam*(1-dst)*(1-y_c)
    const float4* cv = cvec + ((size_t)b * HWn + (size_t)i0g * Wn + j);
    float contrib = 0.0f;
#pragma unroll
    for (int c = 0; c < Gc; ++c) {
        float4 t = cv[(size_t)c * Wn];
        contrib += eg[c][0] * t.x + eg[c][1] * t.y + eg[c][2] * t.z;
    }

    float v = wave_reduce64(contrib);
    __shared__ float wsum[4];
    if ((tid & 63) == 0) wsum[tid >> 6] = v;
    __syncthreads();
    if (tid == 0) atomicAdd(acc, (double)(wsum[0] + wsum[1] + wsum[2] + wsum[3]));
}

// Sum CE block partials + gcrf accumulator -> scalar loss.
__global__ __launch_bounds__(256) void finalize_kernel(
    const float* __restrict__ pc, const double* __restrict__ acc,
    float* __restrict__ out)
{
    int t = threadIdx.x;
    float s = 0.0f;
    if (t < NPREP) s += pc[t];
    if (t + 256 < NPREP) s += pc[t + 256];
    float v = wave_reduce64(s);
    __shared__ float wsum[4];
    if ((t & 63) == 0) wsum[t >> 6] = v;
    __syncthreads();
    if (t == 0) {
        double tot = acc[0] + (double)(wsum[0] + wsum[1] + wsum[2] + wsum[3]);
        out[0] = (float)(tot * (1.0 / (double)(Bn * HWn)));
    }
}

extern "C" void kernel_launch(void* const* d_in, const int* in_sizes, int n_in,
                              void* d_out, int out_size, void* d_ws, size_t ws_size,
                              hipStream_t stream)
{
    const float* logit  = (const float*)d_in[0];
    const int*   target = (const int*)d_in[1];
    const float* image  = (const float*)d_in[2];
    const float* srcmap = (const float*)d_in[3];
    const float* dstmap = (const float*)d_in[4];
    float* out = (float*)d_out;

    const size_t NRECG = (size_t)Bn * PP;   // 66,248 padded records
    double* acc  = (double*)d_ws;
    float*  pc   = (float*)((char*)d_ws + 256);                  // 259 CE partials
    float4* gA   = (float4*)((char*)d_ws + 4096);
    float2* gB   = (float2*)((char*)d_ws + 4096 + NRECG * 16);
    float4* cvec = (float4*)((char*)d_ws + 4096 + NRECG * 24);

    prep_kernel<<<NPREP, 256, 0, stream>>>(logit, target, image, srcmap, dstmap,
                                           gA, gB, cvec, pc, acc);
    dim3 grid(Wn / TJ, (Hn / TI) * Bn, Kc);
    dim3 blk(TJ, 8);
    gcrf_kernel<<<grid, blk, 0, stream>>>(gA, gB, cvec, acc);
    finalize_kernel<<<1, 256, 0, stream>>>(pc, acc, out);
}